// Round 1
// baseline (1088.897 us; speedup 1.0000x reference)
//
#include <hip/hip_runtime.h>
#include <hip/hip_bf16.h>

typedef __attribute__((ext_vector_type(8))) short short8;
typedef __attribute__((ext_vector_type(4))) float floatx4;

#define LDP 72    // LDS staging pitch (ushorts) for 64-wide K tiles: 144B rows, 16B-aligned, ~2-way banks
#define TP  136   // LDS pitch (ushorts) for 128-wide tiles: 272B rows, 16B-aligned

#define ATTN_OFF ((size_t)16 * 2048 * 512)   // out is first in d_out, attn second

__device__ __forceinline__ unsigned short f2bf(float f) {
    union { __hip_bfloat16 h; unsigned short u; } cv;
    cv.h = __float2bfloat16(f);
    return cv.u;
}

__device__ __forceinline__ uint2 f4_to_bf4(float x, float y, float z, float w) {
    uint2 r;
    r.x = (unsigned)f2bf(x) | ((unsigned)f2bf(y) << 16);
    r.y = (unsigned)f2bf(z) | ((unsigned)f2bf(w) << 16);
    return r;
}

// ---------------------------------------------------------------------------
// K1: projections.  out[n,e] = (sum_d x[n,d] * W[e,d]) * c   (NT GEMM, K=512)
// mat 0: qp  (c = 1/sqrt(512) * 512^-0.5 = 1/512, attn scale folded in)
// mat 1: kp  (c = 1/sqrt(512))
// mat 2: vpT (c = 1/sqrt(512)), stored transposed [b][e][tok] for the PV GEMM
// ---------------------------------------------------------------------------
__global__ __launch_bounds__(256, 2)
void proj_kernel(const float* __restrict__ q, const float* __restrict__ k,
                 const float* __restrict__ v, const float* __restrict__ wq,
                 const float* __restrict__ wk, const float* __restrict__ wv,
                 unsigned short* __restrict__ qp, unsigned short* __restrict__ kp,
                 unsigned short* __restrict__ vpT)
{
    const int mat = blockIdx.z;
    const float* __restrict__ x = (mat == 0) ? q : (mat == 1) ? k : v;
    const float* __restrict__ w = (mat == 0) ? wq : (mat == 1) ? wk : wv;
    const float scale = (mat == 0) ? (1.0f / 512.0f) : 0.044194173824159216f;

    const int m0 = blockIdx.x * 128;   // token row (global over 32768)
    const int n0 = blockIdx.y * 128;   // e col

    __shared__ __align__(16) unsigned short sm[2 * 128 * LDP];   // 36864 B
    unsigned short* lds_a = sm;
    unsigned short* lds_b = sm + 128 * LDP;
    unsigned short* lds_t = sm;        // epilogue transpose buf, 128*TP = 17408 <= 18432

    const int t = threadIdx.x;
    const int wave = t >> 6, ln = t & 15, qd = (t >> 4) & 3;
    const int wm = wave >> 1, wn = wave & 1;

    floatx4 acc[4][4];
    for (int mi = 0; mi < 4; ++mi)
        for (int ni = 0; ni < 4; ++ni)
            acc[mi][ni] = (floatx4){0.f, 0.f, 0.f, 0.f};

    for (int kb = 0; kb < 512; kb += 64) {
        for (int i = 0; i < 8; ++i) {
            int lin = t + 256 * i;
            int row = lin >> 4, c4 = lin & 15;
            const float4 a4 = *(const float4*)&x[(size_t)(m0 + row) * 512 + kb + c4 * 4];
            *(uint2*)&lds_a[row * LDP + c4 * 4] = f4_to_bf4(a4.x, a4.y, a4.z, a4.w);
            const float4 b4 = *(const float4*)&w[(size_t)(n0 + row) * 512 + kb + c4 * 4];
            *(uint2*)&lds_b[row * LDP + c4 * 4] = f4_to_bf4(b4.x, b4.y, b4.z, b4.w);
        }
        __syncthreads();
        for (int kk = 0; kk < 2; ++kk) {
            short8 af[4], bg[4];
            for (int mi = 0; mi < 4; ++mi)
                af[mi] = *(const short8*)&lds_a[(wm * 64 + mi * 16 + ln) * LDP + kk * 32 + qd * 8];
            for (int ni = 0; ni < 4; ++ni)
                bg[ni] = *(const short8*)&lds_b[(wn * 64 + ni * 16 + ln) * LDP + kk * 32 + qd * 8];
            for (int mi = 0; mi < 4; ++mi)
                for (int ni = 0; ni < 4; ++ni)
                    acc[mi][ni] = __builtin_amdgcn_mfma_f32_16x16x32_bf16(
                        af[mi], bg[ni], acc[mi][ni], 0, 0, 0);
        }
        __syncthreads();
    }

    // epilogue: repack tile through LDS for coalesced 16B bf16 stores.
    // C/D layout: col = lane&15, row = quad*4 + reg  [m89/m91]
    for (int mi = 0; mi < 4; ++mi)
        for (int ni = 0; ni < 4; ++ni)
            for (int r = 0; r < 4; ++r) {
                float val = acc[mi][ni][r] * scale;
                int row = wm * 64 + mi * 16 + qd * 4 + r;
                int col = wn * 64 + ni * 16 + ln;
                if (mat == 2) lds_t[col * TP + row] = f2bf(val);   // transposed for vpT
                else          lds_t[row * TP + col] = f2bf(val);
            }
    __syncthreads();
    if (mat < 2) {
        unsigned short* dst = (mat == 0) ? qp : kp;
        for (int i = 0; i < 8; ++i) {
            int lin = t + 256 * i;
            int row = lin >> 4, c8 = lin & 15;
            *(uint4*)&dst[(size_t)(m0 + row) * 512 + n0 + c8 * 8] =
                *(const uint4*)&lds_t[row * TP + c8 * 8];
        }
    } else {
        int b = m0 >> 11;
        int tloc = m0 & 2047;
        for (int i = 0; i < 8; ++i) {
            int lin = t + 256 * i;
            int row = lin >> 4, c8 = lin & 15;   // row = e-local
            *(uint4*)&vpT[(size_t)b * 512 * 2048 + (size_t)(n0 + row) * 2048 + tloc + c8 * 8] =
                *(const uint4*)&lds_t[row * TP + c8 * 8];
        }
    }
}

// ---------------------------------------------------------------------------
// K2: dots. p = exp(qp · kp^T) written unnormalized (fp32) into d_out's attn
// region; per-row sums accumulated into lsum via shuffle + LDS + global atomic.
// No max-subtraction: dots ~ N(0,1), max ~5.8, exp fits fp32 easily.
// ---------------------------------------------------------------------------
__global__ __launch_bounds__(256, 2)
void dots_kernel(const unsigned short* __restrict__ qp, const unsigned short* __restrict__ kp,
                 float* __restrict__ attn, float* __restrict__ lsum)
{
    const int b = blockIdx.z;
    const int row0 = blockIdx.y * 128;
    const int col0 = blockIdx.x * 128;

    __shared__ __align__(16) unsigned short sm[2 * 128 * LDP];
    unsigned short* lds_a = sm;
    unsigned short* lds_b = sm + 128 * LDP;
    __shared__ float lds_l[128];

    const int t = threadIdx.x;
    const int wave = t >> 6, ln = t & 15, qd = (t >> 4) & 3;
    const int wm = wave >> 1, wn = wave & 1;

    if (t < 128) lds_l[t] = 0.f;

    const unsigned short* arow = qp + (size_t)(b * 2048 + row0) * 512;
    const unsigned short* brow = kp + (size_t)(b * 2048 + col0) * 512;

    floatx4 acc[4][4];
    for (int mi = 0; mi < 4; ++mi)
        for (int ni = 0; ni < 4; ++ni)
            acc[mi][ni] = (floatx4){0.f, 0.f, 0.f, 0.f};

    for (int kb = 0; kb < 512; kb += 64) {
        for (int i = 0; i < 4; ++i) {
            int lin = t + 256 * i;
            int row = lin >> 3, c8 = lin & 7;
            *(uint4*)&lds_a[row * LDP + c8 * 8] = *(const uint4*)&arow[(size_t)row * 512 + kb + c8 * 8];
            *(uint4*)&lds_b[row * LDP + c8 * 8] = *(const uint4*)&brow[(size_t)row * 512 + kb + c8 * 8];
        }
        __syncthreads();
        for (int kk = 0; kk < 2; ++kk) {
            short8 af[4], bg[4];
            for (int mi = 0; mi < 4; ++mi)
                af[mi] = *(const short8*)&lds_a[(wm * 64 + mi * 16 + ln) * LDP + kk * 32 + qd * 8];
            for (int ni = 0; ni < 4; ++ni)
                bg[ni] = *(const short8*)&lds_b[(wn * 64 + ni * 16 + ln) * LDP + kk * 32 + qd * 8];
            for (int mi = 0; mi < 4; ++mi)
                for (int ni = 0; ni < 4; ++ni)
                    acc[mi][ni] = __builtin_amdgcn_mfma_f32_16x16x32_bf16(
                        af[mi], bg[ni], acc[mi][ni], 0, 0, 0);
        }
        __syncthreads();
    }

    float* attnb = attn + (size_t)(b * 2048 + row0) * 2048 + col0;
    for (int mi = 0; mi < 4; ++mi) {
        float s[4] = {0.f, 0.f, 0.f, 0.f};
        for (int ni = 0; ni < 4; ++ni) {
            int colL = wn * 64 + ni * 16 + ln;
            for (int r = 0; r < 4; ++r) {
                float p = __expf(acc[mi][ni][r]);
                int rowL = wm * 64 + mi * 16 + qd * 4 + r;
                attnb[(size_t)rowL * 2048 + colL] = p;
                s[r] += p;
            }
        }
        // sum over the 16 lanes holding this row's 16 columns (xor within quad)
        for (int r = 0; r < 4; ++r) {
            float vv = s[r];
            vv += __shfl_xor(vv, 1);
            vv += __shfl_xor(vv, 2);
            vv += __shfl_xor(vv, 4);
            vv += __shfl_xor(vv, 8);
            if (ln == 0) atomicAdd(&lds_l[wm * 64 + mi * 16 + qd * 4 + r], vv);
        }
    }
    __syncthreads();
    if (t < 128) atomicAdd(&lsum[b * 2048 + row0 + t], lds_l[t]);
}

// ---------------------------------------------------------------------------
// K3: normalize attn in place (attn = p / l) and compute out = attn @ vp via
// MFMA with vpT (NT form). 64-row q-tile per block, acc = 64x512 fp32.
// ---------------------------------------------------------------------------
__global__ __launch_bounds__(256, 2)
void out_kernel(const unsigned short* __restrict__ vpT, float* __restrict__ attn,
                const float* __restrict__ lsum, float* __restrict__ out)
{
    const int b = blockIdx.y;
    const int row0 = blockIdx.x * 64;

    __shared__ __align__(16) unsigned short p_lds[64 * TP];    // 17408 B
    __shared__ __align__(16) unsigned short v_lds[128 * TP];   // 34816 B
    __shared__ float inv_l[64];

    const int t = threadIdx.x;
    const int wave = t >> 6, ln = t & 15, qd = (t >> 4) & 3;

    if (t < 64) inv_l[t] = 1.0f / lsum[b * 2048 + row0 + t];

    floatx4 acc[4][8];
    for (int mi = 0; mi < 4; ++mi)
        for (int j = 0; j < 8; ++j)
            acc[mi][j] = (floatx4){0.f, 0.f, 0.f, 0.f};

    float* attnb = attn + (size_t)(b * 2048 + row0) * 2048;
    const unsigned short* vb = vpT + (size_t)b * 512 * 2048;

    for (int kc = 0; kc < 2048; kc += 128) {
        __syncthreads();   // prev iter's MFMA reads of p_lds done; inv_l visible (1st iter)
        for (int i = 0; i < 8; ++i) {
            int lin = t + 256 * i;
            int row = lin >> 5, c4 = lin & 31;
            float* ad = &attnb[(size_t)row * 2048 + kc + c4 * 4];
            float4 p4 = *(float4*)ad;
            float il = inv_l[row];
            p4.x *= il; p4.y *= il; p4.z *= il; p4.w *= il;
            *(float4*)ad = p4;                                   // finalize attn output
            *(uint2*)&p_lds[row * TP + c4 * 4] = f4_to_bf4(p4.x, p4.y, p4.z, p4.w);
        }
        for (int nh = 0; nh < 4; ++nh) {
            __syncthreads();   // prev nh MFMA done before v_lds overwrite; p_lds visible at nh=0
            for (int i = 0; i < 8; ++i) {
                int lin = t + 256 * i;
                int row = lin >> 4, c8 = lin & 15;   // row = e-local within 128-chunk
                *(uint4*)&v_lds[row * TP + c8 * 8] =
                    *(const uint4*)&vb[(size_t)(nh * 128 + row) * 2048 + kc + c8 * 8];
            }
            __syncthreads();
            for (int ks = 0; ks < 4; ++ks) {
                short8 af[4];
                for (int mi = 0; mi < 4; ++mi)
                    af[mi] = *(const short8*)&p_lds[(mi * 16 + ln) * TP + ks * 32 + qd * 8];
                for (int ni = 0; ni < 2; ++ni) {
                    short8 bg = *(const short8*)&v_lds[(wave * 32 + ni * 16 + ln) * TP + ks * 32 + qd * 8];
                    for (int mi = 0; mi < 4; ++mi)
                        acc[mi][nh * 2 + ni] = __builtin_amdgcn_mfma_f32_16x16x32_bf16(
                            af[mi], bg, acc[mi][nh * 2 + ni], 0, 0, 0);
                }
            }
        }
    }

    float* outb = out + (size_t)(b * 2048 + row0) * 512;
    for (int mi = 0; mi < 4; ++mi)
        for (int j = 0; j < 8; ++j) {
            int col = (j >> 1) * 128 + wave * 32 + (j & 1) * 16 + ln;
            for (int r = 0; r < 4; ++r) {
                int rowL = mi * 16 + qd * 4 + r;
                outb[(size_t)rowL * 512 + col] = acc[mi][j][r];
            }
        }
}

extern "C" void kernel_launch(void* const* d_in, const int* in_sizes, int n_in,
                              void* d_out, int out_size, void* d_ws, size_t ws_size,
                              hipStream_t stream) {
    const float* q  = (const float*)d_in[0];
    const float* k  = (const float*)d_in[1];
    const float* v  = (const float*)d_in[2];
    const float* wq = (const float*)d_in[3];
    const float* wk = (const float*)d_in[4];
    const float* wv = (const float*)d_in[5];

    // workspace layout (bf16 projections + row sums): ~96.1 MiB total
    unsigned short* qp  = (unsigned short*)d_ws;
    unsigned short* kp  = qp + (size_t)32768 * 512;
    unsigned short* vpT = kp + (size_t)32768 * 512;
    float* lsum = (float*)(vpT + (size_t)16 * 512 * 2048);

    float* out  = (float*)d_out;                 // [16,2048,512]
    float* attn = out + ATTN_OFF;                // [16,2048,2048]

    hipMemsetAsync(lsum, 0, (size_t)16 * 2048 * sizeof(float), stream);

    proj_kernel<<<dim3(256, 4, 3), 256, 0, stream>>>(q, k, v, wq, wk, wv, qp, kp, vpT);
    dots_kernel<<<dim3(16, 16, 16), 256, 0, stream>>>(qp, kp, attn, lsum);
    out_kernel<<<dim3(32, 16), 256, 0, stream>>>(vpT, attn, lsum, out);
}

// Round 2
// 917.798 us; speedup vs baseline: 1.1864x; 1.1864x over previous
//
#include <hip/hip_runtime.h>
#include <hip/hip_bf16.h>

typedef __attribute__((ext_vector_type(8))) short short8;
typedef __attribute__((ext_vector_type(4))) float floatx4;

#define LDP 72    // LDS staging pitch (ushorts) for 64-wide K tiles: 144B rows, 16B-aligned, ~2-way banks
#define TP  136   // LDS pitch (ushorts) for 128-wide tiles: 272B rows, 16B-aligned
#define PP  40    // out_kernel P-tile pitch (ushorts): 5 granules/row -> uniform bank groups

#define ATTN_OFF ((size_t)16 * 2048 * 512)   // out is first in d_out, attn second

__device__ __forceinline__ unsigned short f2bf(float f) {
    union { __hip_bfloat16 h; unsigned short u; } cv;
    cv.h = __float2bfloat16(f);
    return cv.u;
}

__device__ __forceinline__ uint2 f4_to_bf4(float x, float y, float z, float w) {
    uint2 r;
    r.x = (unsigned)f2bf(x) | ((unsigned)f2bf(y) << 16);
    r.y = (unsigned)f2bf(z) | ((unsigned)f2bf(w) << 16);
    return r;
}

// ---------------------------------------------------------------------------
// K1: projections.  out[n,e] = (sum_d x[n,d] * W[e,d]) * c   (NT GEMM, K=512)
// mat 0: qp  (c = 1/sqrt(512) * 512^-0.5 = 1/512, attn scale folded in)
// mat 1: kp  (c = 1/sqrt(512))
// mat 2: vpT (c = 1/sqrt(512)), stored transposed [b][e][tok] for the PV GEMM
// ---------------------------------------------------------------------------
__global__ __launch_bounds__(256, 2)
void proj_kernel(const float* __restrict__ q, const float* __restrict__ k,
                 const float* __restrict__ v, const float* __restrict__ wq,
                 const float* __restrict__ wk, const float* __restrict__ wv,
                 unsigned short* __restrict__ qp, unsigned short* __restrict__ kp,
                 unsigned short* __restrict__ vpT)
{
    const int mat = blockIdx.z;
    const float* __restrict__ x = (mat == 0) ? q : (mat == 1) ? k : v;
    const float* __restrict__ w = (mat == 0) ? wq : (mat == 1) ? wk : wv;
    const float scale = (mat == 0) ? (1.0f / 512.0f) : 0.044194173824159216f;

    const int m0 = blockIdx.x * 128;   // token row (global over 32768)
    const int n0 = blockIdx.y * 128;   // e col

    __shared__ __align__(16) unsigned short sm[2 * 128 * LDP];   // 36864 B
    unsigned short* lds_a = sm;
    unsigned short* lds_b = sm + 128 * LDP;
    unsigned short* lds_t = sm;        // epilogue transpose buf, 128*TP = 17408 <= 18432

    const int t = threadIdx.x;
    const int wave = t >> 6, ln = t & 15, qd = (t >> 4) & 3;
    const int wm = wave >> 1, wn = wave & 1;

    floatx4 acc[4][4];
    for (int mi = 0; mi < 4; ++mi)
        for (int ni = 0; ni < 4; ++ni)
            acc[mi][ni] = (floatx4){0.f, 0.f, 0.f, 0.f};

    for (int kb = 0; kb < 512; kb += 64) {
        for (int i = 0; i < 8; ++i) {
            int lin = t + 256 * i;
            int row = lin >> 4, c4 = lin & 15;
            const float4 a4 = *(const float4*)&x[(size_t)(m0 + row) * 512 + kb + c4 * 4];
            *(uint2*)&lds_a[row * LDP + c4 * 4] = f4_to_bf4(a4.x, a4.y, a4.z, a4.w);
            const float4 b4 = *(const float4*)&w[(size_t)(n0 + row) * 512 + kb + c4 * 4];
            *(uint2*)&lds_b[row * LDP + c4 * 4] = f4_to_bf4(b4.x, b4.y, b4.z, b4.w);
        }
        __syncthreads();
        for (int kk = 0; kk < 2; ++kk) {
            short8 af[4], bg[4];
            for (int mi = 0; mi < 4; ++mi)
                af[mi] = *(const short8*)&lds_a[(wm * 64 + mi * 16 + ln) * LDP + kk * 32 + qd * 8];
            for (int ni = 0; ni < 4; ++ni)
                bg[ni] = *(const short8*)&lds_b[(wn * 64 + ni * 16 + ln) * LDP + kk * 32 + qd * 8];
            for (int mi = 0; mi < 4; ++mi)
                for (int ni = 0; ni < 4; ++ni)
                    acc[mi][ni] = __builtin_amdgcn_mfma_f32_16x16x32_bf16(
                        af[mi], bg[ni], acc[mi][ni], 0, 0, 0);
        }
        __syncthreads();
    }

    // epilogue: repack tile through LDS for coalesced 16B bf16 stores.
    // C/D layout: col = lane&15, row = quad*4 + reg  [m89/m91]
    for (int mi = 0; mi < 4; ++mi)
        for (int ni = 0; ni < 4; ++ni)
            for (int r = 0; r < 4; ++r) {
                float val = acc[mi][ni][r] * scale;
                int row = wm * 64 + mi * 16 + qd * 4 + r;
                int col = wn * 64 + ni * 16 + ln;
                if (mat == 2) lds_t[col * TP + row] = f2bf(val);   // transposed for vpT
                else          lds_t[row * TP + col] = f2bf(val);
            }
    __syncthreads();
    if (mat < 2) {
        unsigned short* dst = (mat == 0) ? qp : kp;
        for (int i = 0; i < 8; ++i) {
            int lin = t + 256 * i;
            int row = lin >> 4, c8 = lin & 15;
            *(uint4*)&dst[(size_t)(m0 + row) * 512 + n0 + c8 * 8] =
                *(const uint4*)&lds_t[row * TP + c8 * 8];
        }
    } else {
        int b = m0 >> 11;
        int tloc = m0 & 2047;
        for (int i = 0; i < 8; ++i) {
            int lin = t + 256 * i;
            int row = lin >> 4, c8 = lin & 15;   // row = e-local
            *(uint4*)&vpT[(size_t)b * 512 * 2048 + (size_t)(n0 + row) * 2048 + tloc + c8 * 8] =
                *(const uint4*)&lds_t[row * TP + c8 * 8];
        }
    }
}

// ---------------------------------------------------------------------------
// K2: dots. p = exp(qp · kp^T) written unnormalized (fp32) into d_out's attn
// region; per-row sums accumulated into lsum via shuffle + LDS + global atomic.
// No max-subtraction: dots ~ N(0,1), max ~5.8, exp fits fp32 easily.
// ---------------------------------------------------------------------------
__global__ __launch_bounds__(256, 2)
void dots_kernel(const unsigned short* __restrict__ qp, const unsigned short* __restrict__ kp,
                 float* __restrict__ attn, float* __restrict__ lsum)
{
    const int b = blockIdx.z;
    const int row0 = blockIdx.y * 128;
    const int col0 = blockIdx.x * 128;

    __shared__ __align__(16) unsigned short sm[2 * 128 * LDP];
    unsigned short* lds_a = sm;
    unsigned short* lds_b = sm + 128 * LDP;
    __shared__ float lds_l[128];

    const int t = threadIdx.x;
    const int wave = t >> 6, ln = t & 15, qd = (t >> 4) & 3;
    const int wm = wave >> 1, wn = wave & 1;

    if (t < 128) lds_l[t] = 0.f;

    const unsigned short* arow = qp + (size_t)(b * 2048 + row0) * 512;
    const unsigned short* brow = kp + (size_t)(b * 2048 + col0) * 512;

    floatx4 acc[4][4];
    for (int mi = 0; mi < 4; ++mi)
        for (int ni = 0; ni < 4; ++ni)
            acc[mi][ni] = (floatx4){0.f, 0.f, 0.f, 0.f};

    for (int kb = 0; kb < 512; kb += 64) {
        for (int i = 0; i < 4; ++i) {
            int lin = t + 256 * i;
            int row = lin >> 3, c8 = lin & 7;
            *(uint4*)&lds_a[row * LDP + c8 * 8] = *(const uint4*)&arow[(size_t)row * 512 + kb + c8 * 8];
            *(uint4*)&lds_b[row * LDP + c8 * 8] = *(const uint4*)&brow[(size_t)row * 512 + kb + c8 * 8];
        }
        __syncthreads();
        for (int kk = 0; kk < 2; ++kk) {
            short8 af[4], bg[4];
            for (int mi = 0; mi < 4; ++mi)
                af[mi] = *(const short8*)&lds_a[(wm * 64 + mi * 16 + ln) * LDP + kk * 32 + qd * 8];
            for (int ni = 0; ni < 4; ++ni)
                bg[ni] = *(const short8*)&lds_b[(wn * 64 + ni * 16 + ln) * LDP + kk * 32 + qd * 8];
            for (int mi = 0; mi < 4; ++mi)
                for (int ni = 0; ni < 4; ++ni)
                    acc[mi][ni] = __builtin_amdgcn_mfma_f32_16x16x32_bf16(
                        af[mi], bg[ni], acc[mi][ni], 0, 0, 0);
        }
        __syncthreads();
    }

    float* attnb = attn + (size_t)(b * 2048 + row0) * 2048 + col0;
    for (int mi = 0; mi < 4; ++mi) {
        float s[4] = {0.f, 0.f, 0.f, 0.f};
        for (int ni = 0; ni < 4; ++ni) {
            int colL = wn * 64 + ni * 16 + ln;
            for (int r = 0; r < 4; ++r) {
                float p = __expf(acc[mi][ni][r]);
                int rowL = wm * 64 + mi * 16 + qd * 4 + r;
                attnb[(size_t)rowL * 2048 + colL] = p;
                s[r] += p;
            }
        }
        // sum over the 16 lanes holding this row's 16 columns (xor within quad)
        for (int r = 0; r < 4; ++r) {
            float vv = s[r];
            vv += __shfl_xor(vv, 1);
            vv += __shfl_xor(vv, 2);
            vv += __shfl_xor(vv, 4);
            vv += __shfl_xor(vv, 8);
            if (ln == 0) atomicAdd(&lds_l[wm * 64 + mi * 16 + qd * 4 + r], vv);
        }
    }
    __syncthreads();
    if (t < 128) atomicAdd(&lsum[b * 2048 + row0 + t], lds_l[t]);
}

// ---------------------------------------------------------------------------
// K3 v2: one 512-thread block per 128-row strip (full N=512, K=2048).
// grid (batch, rowtile) so XCD = batch%8 -> each XCD's L2 holds 2 vpT slices.
// Per K=32 iter: bg (vpT) direct global->VGPR (L2-resident, no LDS staging);
// P fp32 read -> *inv_l -> written back in place (final attn) -> normalized
// bf16 into double-buffered LDS (pitch 40 = 5 granules, uniform bank groups).
// Normalized P in LDS => out = acc directly, no epilogue rescale.
// ---------------------------------------------------------------------------
__global__ __launch_bounds__(512, 2)
void out_kernel(const unsigned short* __restrict__ vpT, float* __restrict__ attn,
                const float* __restrict__ lsum, float* __restrict__ out)
{
    const int b  = blockIdx.x;          // batch on .x -> XCD = b%8 (L2 locality)
    const int r0 = blockIdx.y * 128;

    __shared__ __align__(16) unsigned short p_lds[2][128 * PP];   // 20480 B total

    const int t = threadIdx.x;
    const int wave = t >> 6, ln = t & 15, qd = (t >> 4) & 3;
    const int wm = wave >> 2, wn = wave & 3;     // 2 x 4 wave grid: 64 rows x 128 cols each

    const int prow = t >> 2;            // 0..127: this thread's P row (fixed)
    const int pcol = (t & 3) * 8;       // 0,8,16,24
    const float il = 1.0f / lsum[b * 2048 + r0 + prow];

    float* pbase = attn + (size_t)(b * 2048 + r0 + prow) * 2048 + pcol;
    const unsigned short* vb = vpT + (size_t)b * 512 * 2048;

    floatx4 acc[4][8];
    #pragma unroll
    for (int mi = 0; mi < 4; ++mi)
        #pragma unroll
        for (int ni = 0; ni < 8; ++ni)
            acc[mi][ni] = (floatx4){0.f, 0.f, 0.f, 0.f};

    // prologue: stage k-chunk 0 into buf 0
    {
        float4 pa = *(const float4*)(pbase);
        float4 pb = *(const float4*)(pbase + 4);
        pa.x *= il; pa.y *= il; pa.z *= il; pa.w *= il;
        pb.x *= il; pb.y *= il; pb.z *= il; pb.w *= il;
        *(float4*)(pbase)     = pa;              // final attn
        *(float4*)(pbase + 4) = pb;
        uint2 lo = f4_to_bf4(pa.x, pa.y, pa.z, pa.w);
        uint2 hi = f4_to_bf4(pb.x, pb.y, pb.z, pb.w);
        uint4 pk = {lo.x, lo.y, hi.x, hi.y};
        *(uint4*)&p_lds[0][prow * PP + pcol] = pk;
    }

    for (int i = 0; i < 64; ++i) {
        const int kc = i * 32;
        const int buf = i & 1;
        __syncthreads();                          // stage(i) visible; buf^1 free

        // B fragments: direct global (L2-hot vpT rows), issue first
        short8 bg[8];
        #pragma unroll
        for (int ni = 0; ni < 8; ++ni)
            bg[ni] = *(const short8*)&vb[(size_t)(wn * 128 + ni * 16 + ln) * 2048 + kc + qd * 8];

        // next P chunk (HBM) — issued before MFMA so it flies during compute
        float4 pa, pb;
        if (i < 63) {
            pa = *(const float4*)(pbase + kc + 32);
            pb = *(const float4*)(pbase + kc + 36);
        }

        short8 af[4];
        #pragma unroll
        for (int mi = 0; mi < 4; ++mi)
            af[mi] = *(const short8*)&p_lds[buf][(wm * 64 + mi * 16 + ln) * PP + qd * 8];

        #pragma unroll
        for (int ni = 0; ni < 8; ++ni)
            #pragma unroll
            for (int mi = 0; mi < 4; ++mi)
                acc[mi][ni] = __builtin_amdgcn_mfma_f32_16x16x32_bf16(
                    af[mi], bg[ni], acc[mi][ni], 0, 0, 0);

        // finish staging chunk i+1 into buf^1 (attn write + LDS pack)
        if (i < 63) {
            pa.x *= il; pa.y *= il; pa.z *= il; pa.w *= il;
            pb.x *= il; pb.y *= il; pb.z *= il; pb.w *= il;
            *(float4*)(pbase + kc + 32) = pa;    // final attn
            *(float4*)(pbase + kc + 36) = pb;
            uint2 lo = f4_to_bf4(pa.x, pa.y, pa.z, pa.w);
            uint2 hi = f4_to_bf4(pb.x, pb.y, pb.z, pb.w);
            uint4 pk = {lo.x, lo.y, hi.x, hi.y};
            *(uint4*)&p_lds[buf ^ 1][prow * PP + pcol] = pk;
        }
    }

    // epilogue: acc is already normalized out
    float* outb = out + (size_t)(b * 2048 + r0) * 512;
    #pragma unroll
    for (int mi = 0; mi < 4; ++mi)
        #pragma unroll
        for (int ni = 0; ni < 8; ++ni) {
            int col = wn * 128 + ni * 16 + ln;
            #pragma unroll
            for (int r = 0; r < 4; ++r) {
                int row = wm * 64 + mi * 16 + qd * 4 + r;
                outb[(size_t)row * 512 + col] = acc[mi][ni][r];
            }
        }
}

extern "C" void kernel_launch(void* const* d_in, const int* in_sizes, int n_in,
                              void* d_out, int out_size, void* d_ws, size_t ws_size,
                              hipStream_t stream) {
    const float* q  = (const float*)d_in[0];
    const float* k  = (const float*)d_in[1];
    const float* v  = (const float*)d_in[2];
    const float* wq = (const float*)d_in[3];
    const float* wk = (const float*)d_in[4];
    const float* wv = (const float*)d_in[5];

    // workspace layout (bf16 projections + row sums): ~96.1 MiB total
    unsigned short* qp  = (unsigned short*)d_ws;
    unsigned short* kp  = qp + (size_t)32768 * 512;
    unsigned short* vpT = kp + (size_t)32768 * 512;
    float* lsum = (float*)(vpT + (size_t)16 * 512 * 2048);

    float* out  = (float*)d_out;                 // [16,2048,512]
    float* attn = out + ATTN_OFF;                // [16,2048,2048]

    hipMemsetAsync(lsum, 0, (size_t)16 * 2048 * sizeof(float), stream);

    proj_kernel<<<dim3(256, 4, 3), 256, 0, stream>>>(q, k, v, wq, wk, wv, qp, kp, vpT);
    dots_kernel<<<dim3(16, 16, 16), 256, 0, stream>>>(qp, kp, attn, lsum);
    out_kernel<<<dim3(16, 16), 512, 0, stream>>>(vpT, attn, lsum, out);
}